// Round 13
// baseline (422.110 us; speedup 1.0000x reference)
//
#include <hip/hip_runtime.h>

#define NDIM 14
#define HDIM 64
#define NB 512         // scatter bucket slots (nbu <= NB used)
#define EPB 16         // edges per thread in k_bin
#define GSTR 72        // padded col stride (halfs) for LDS-staged f16 weights

typedef __attribute__((ext_vector_type(8))) _Float16 half8;
typedef __attribute__((ext_vector_type(2))) __fp16 fp16x2;   // builtin interop type
typedef __attribute__((ext_vector_type(4))) float f32x4;

static __device__ __forceinline__ float sigmoidf_(float x) { return 1.f / (1.f + __expf(-x)); }
static __device__ __forceinline__ float lrelu_(float x) { return x > 0.f ? x : 0.2f * x; }

static __device__ __forceinline__ float readlane_f(float x, int lane) {
  return __int_as_float(__builtin_amdgcn_readlane(__float_as_int(x), lane));
}

template <int CTRL>
static __device__ __forceinline__ float dpp_add_f(float x) {
  int v = __builtin_amdgcn_update_dpp(0, __float_as_int(x), CTRL, 0xF, 0xF, true);
  return x + __int_as_float(v);
}

// f32 sum over each 16-lane DPP row
static __device__ __forceinline__ float reduce16(float p) {
  p = dpp_add_f<0xB1>(p);
  p = dpp_add_f<0x4E>(p);
  p = dpp_add_f<0x141>(p);
  p = dpp_add_f<0x140>(p);
  return p;
}
// f32 sum within each 32-lane half
static __device__ __forceinline__ float head_reduce32(float p) {
  p = reduce16(p);
  p += __int_as_float(__builtin_amdgcn_ds_swizzle(__float_as_int(p), 0x401F));
  return p;
}
static __device__ __forceinline__ float full_reduce64(float p) {
  p = head_reduce32(p);
  p += __shfl_xor(p, 32, 64);
  return p;
}

// ---- packed f16 helpers ----
static __device__ __forceinline__ unsigned pk_add(unsigned a, unsigned b) {
  unsigned d; asm("v_pk_add_f16 %0, %1, %2" : "=v"(d) : "v"(a), "v"(b)); return d;
}
static __device__ __forceinline__ unsigned pk_mul(unsigned a, unsigned b) {
  unsigned d; asm("v_pk_mul_f16 %0, %1, %2" : "=v"(d) : "v"(a), "v"(b)); return d;
}
static __device__ __forceinline__ unsigned pk_max(unsigned a, unsigned b) {
  unsigned d; asm("v_pk_max_f16 %0, %1, %2" : "=v"(d) : "v"(a), "v"(b)); return d;
}
static __device__ __forceinline__ unsigned cvt_pk_u(float a, float b) {
  fp16x2 h = __builtin_amdgcn_cvt_pkrtz(a, b);
  unsigned u; __builtin_memcpy(&u, &h, 4); return u;
}
static __device__ __forceinline__ fp16x2 as_h2(unsigned u) {
  fp16x2 h; __builtin_memcpy(&h, &u, 4); return h;
}
static __device__ __forceinline__ float cvt_lo(unsigned u) {
  float r; asm("v_cvt_f32_f16 %0, %1" : "=v"(r) : "v"(u)); return r;
}
template <int CTRL>
static __device__ __forceinline__ unsigned pk_dpp_add(unsigned x) {
  unsigned v = (unsigned)__builtin_amdgcn_update_dpp(0, (int)x, CTRL, 0xF, 0xF, true);
  return pk_add(x, v);
}
// packed f16 sum within each 32-lane half: 4 DPP + 1 swizzle
static __device__ __forceinline__ unsigned pk_reduce32(unsigned p) {
  p = pk_dpp_add<0xB1>(p);     // xor1
  p = pk_dpp_add<0x4E>(p);     // xor2
  p = pk_dpp_add<0x141>(p);    // 8-group mirror
  p = pk_dpp_add<0x140>(p);    // 16-group mirror
  p = pk_add(p, (unsigned)__builtin_amdgcn_ds_swizzle((int)p, 0x401F)); // xor16
  return p;
}

// ======================= CSR build (direct-binned, padded buckets) =======================
// bin edges into per-bucket padded slices; block-local LDS counts + bulk claims
__global__ void __launch_bounds__(256) k_bin(const int* __restrict__ ei,
                      long long* __restrict__ pairs, int* __restrict__ bucket_cur,
                      int E, int bsh) {
  __shared__ int h[NB];
  __shared__ int gb[NB];
  int t = threadIdx.x;
  for (int i = t; i < NB; i += 256) h[i] = 0;
  __syncthreads();
  int c0 = blockIdx.x * (256 * EPB);
  long long pr[EPB];
  int br[EPB];
#pragma unroll
  for (int i = 0; i < EPB; ++i) {
    int e = c0 + t + i * 256;
    if (e < E) {
      int s = ei[e], d = ei[E + e];
      int b = d >> bsh;
      int r = atomicAdd(&h[b], 1);
      pr[i] = ((long long)d << 32) | (unsigned)s;
      br[i] = b | (r << 9);
    } else br[i] = -1;
  }
  __syncthreads();
  for (int i = t; i < NB; i += 256)
    if (h[i]) gb[i] = atomicAdd(&bucket_cur[i], h[i]);
  __syncthreads();
#pragma unroll
  for (int i = 0; i < EPB; ++i) {
    if (br[i] >= 0) pairs[gb[br[i] & (NB - 1)] + (br[i] >> 9)] = pr[i];
  }
}

// per-bucket CSR: degree hist + scan + placement in LDS. One block per bucket.
__global__ void __launch_bounds__(256) k_csr(const long long* __restrict__ pairs,
                      const int* __restrict__ bcur_final, int* __restrict__ row_off,
                      int* __restrict__ deg, int* __restrict__ csr_src,
                      int N, int bsh, int cap) {
  __shared__ int h[1024];
  __shared__ int cu[1024];
  __shared__ int wtot[4];
  int b = blockIdx.x;
  int node0 = b << bsh;
  int range = 1 << bsh;
  int nr = N - node0; if (nr > range) nr = range;
  if (nr <= 0) return;
  int e0 = b * cap, e1 = bcur_final[b];
  int tid = threadIdx.x;
  for (int i = tid; i < range; i += 256) h[i] = 0;
  __syncthreads();
  for (int e = e0 + tid; e < e1; e += 256)
    atomicAdd(&h[(int)(pairs[e] >> 32) - node0], 1);
  __syncthreads();
  if (range == 256) {
    int lane = tid & 63, wid = tid >> 6;
    int v = (tid < nr) ? h[tid] : 0;
    int x = v;
#pragma unroll
    for (int m = 1; m <= 32; m <<= 1) {
      int t2 = __shfl_up(x, m, 64);
      if (lane >= m) x += t2;
    }
    if (lane == 63) wtot[wid] = x;
    __syncthreads();
    int woff = 0;
#pragma unroll
    for (int w = 0; w < 4; ++w) woff += (w < wid) ? wtot[w] : 0;
    int excl = woff + x - v;
    if (tid < nr) {
      row_off[node0 + tid] = e0 + excl;
      deg[node0 + tid] = v;
      cu[tid] = excl;
    }
  } else {
    if (tid == 0) {
      int acc = 0;
      for (int i = 0; i < nr; ++i) {
        row_off[node0 + i] = e0 + acc;
        deg[node0 + i] = h[i];
        cu[i] = acc;
        acc += h[i];
      }
    }
  }
  __syncthreads();
  for (int e = e0 + tid; e < e1; e += 256) {
    long long pk = pairs[e];
    int d = (int)(pk >> 32), s = (int)pk;
    int p = atomicAdd(&cu[d - node0], 1);
    csr_src[e0 + p] = s;
  }
}

// ======================= merged weight prep + bcur init =======================
__global__ void k_wprep(const float* __restrict__ projW, const float* __restrict__ projB,
                        const float* __restrict__ Wl1, const float* __restrict__ Wr1,
                        const float* __restrict__ Wi, const float* __restrict__ Wl2,
                        const float* __restrict__ Wr2,
                        float* __restrict__ Wfl, float* __restrict__ Wfr,
                        float* __restrict__ bfl, float* __restrict__ bfr,
                        _Float16* __restrict__ Wt, _Float16* __restrict__ Wb,
                        int* __restrict__ bcur, int cap) {
  int blk = blockIdx.x;
  if (blk < 4) {
    int t = blk * 256 + threadIdx.x;
    int total = (NDIM + 1) * HDIM;
    if (t >= total) return;
    int r = t / HDIM, c = t % HDIM;
    float al = 0.f, ar = 0.f;
    if (r < NDIM) {
      for (int k = 0; k < HDIM; ++k) {
        float w = projW[r * HDIM + k];
        al += w * Wl1[k * HDIM + c];
        ar += w * Wr1[k * HDIM + c];
      }
      Wfl[r * HDIM + c] = al;
      Wfr[r * HDIM + c] = ar;
    } else {
      for (int k = 0; k < HDIM; ++k) {
        float w = projB[k];
        al += w * Wl1[k * HDIM + c];
        ar += w * Wr1[k * HDIM + c];
      }
      bfl[c] = al;
      bfr[c] = ar;
    }
  } else if (blk < 52) {
    int t = (blk - 4) * 256 + threadIdx.x;
    if (t >= 192 * 64) return;
    int col = t / 64, row = t % 64;
    Wt[col * GSTR + row] = (_Float16)Wi[row * 192 + col];
  } else if (blk < 84) {
    int t = (blk - 52) * 256 + threadIdx.x;
    if (t >= 128 * 64) return;
    int col = t >> 6, row = t & 63;
    float v = (col < 64) ? Wl2[row * 64 + col] : Wr2[row * 64 + (col - 64)];
    Wb[col * GSTR + row] = (_Float16)v;
  } else {
    int i = (blk - 84) * 256 + threadIdx.x;
    if (i < NB) bcur[i] = i * cap;
  }
}

// ======================= k1: XL1(f16)/XR1(f32) from node features =======================
__global__ void k1_xlxr(const float* __restrict__ nf, const float* __restrict__ Wfl,
                        const float* __restrict__ Wfr, const float* __restrict__ bfl,
                        const float* __restrict__ bfr, _Float16* __restrict__ XL16,
                        float* __restrict__ XR, int N) {
  int n = blockIdx.x * (blockDim.x >> 6) + (threadIdx.x >> 6);
  int j = threadIdx.x & 63;
  if (n >= N) return;
  float nfv = (j < NDIM) ? nf[n * NDIM + j] : 0.f;
  float al = bfl[j], ar = bfr[j];
#pragma unroll
  for (int k = 0; k < NDIM; ++k) {
    float xk = readlane_f(nfv, k);
    al += xk * Wfl[k * HDIM + j];
    ar += xk * Wfr[k * HDIM + j];
  }
  XL16[n * HDIM + j] = (_Float16)al;
  XR[n * HDIM + j] = ar;
}

// ======================= k_agg: 2 nodes/wave, packed-f16, fully masked path =======================
// load 8 pairs (16 edges) of node-chunk; OOB slots read node 0 (valid), masked in PROC
#define LOAD8G(xb_, sidx_, g_)                                   \
  _Pragma("unroll") for (int u = 0; u < 8; ++u) {                \
    int pi_ = (g_) * 8 + u;                                      \
    int sa_ = __builtin_amdgcn_readlane(sidx_, 2 * pi_);         \
    int sb_ = __builtin_amdgcn_readlane(sidx_, 2 * pi_ + 1);     \
    unsigned ua_ = XLu[((unsigned)sa_ << 6) + ju];               \
    unsigned ub_ = XLu[((unsigned)sb_ << 6) + ju];               \
    xb_[u] = __builtin_amdgcn_perm(ub_, ua_, 0x05040100u);       \
  }

#define PROC8G(xb_, g_, m_, xrpk_, a0_, a1_, d0_, d1_)           \
  _Pragma("unroll") for (int u = 0; u < 8; ++u) {                \
    int pi_ = (g_) * 8 + u;                                      \
    unsigned t_ = pk_add(xb_[u], xrpk_);                         \
    unsigned lr_ = pk_max(t_, pk_mul(t_, c02_pk));               \
    unsigned sc_ = pk_mul(lr_, att_pk);                          \
    sc_ = pk_reduce32(sc_);                                      \
    float sfa_ = cvt_lo(sc_), sfb_ = cvt_lo(sc_ >> 16);          \
    float ea_ = __expf(sfa_), eb_ = __expf(sfb_);                \
    ea_ = (2 * pi_ < (m_)) ? ea_ : 0.f;                          \
    eb_ = (2 * pi_ + 1 < (m_)) ? eb_ : 0.f;                      \
    fp16x2 exk_ = __builtin_amdgcn_cvt_pkrtz(ea_, eb_);          \
    if (u & 1) {                                                 \
      a1_ = __builtin_amdgcn_fdot2(as_h2(xb_[u]), exk_, a1_, false); \
      d1_ = __builtin_amdgcn_fdot2(exk_, one_pk, d1_, false);    \
    } else {                                                     \
      a0_ = __builtin_amdgcn_fdot2(as_h2(xb_[u]), exk_, a0_, false); \
      d0_ = __builtin_amdgcn_fdot2(exk_, one_pk, d0_, false);    \
    }                                                            \
  }

__global__ void k_agg(const int* __restrict__ csr_src, const int* __restrict__ row_off,
                      const int* __restrict__ deg, const _Float16* __restrict__ XL16,
                      const float* __restrict__ XR, const float* __restrict__ att,
                      const float* __restrict__ gb, const float* __restrict__ lng,
                      const float* __restrict__ lnb, float* __restrict__ Y, int N) {
  int wid = blockIdx.x * (blockDim.x >> 6) + (threadIdx.x >> 6);
  int j = threadIdx.x & 63;
  int nA = wid * 2;
  if (nA >= N) return;
  int nB = nA + 1;
  bool hasB = nB < N;
  int nBc = hasB ? nB : nA;

  float attv = att[j];
  unsigned att_pk = cvt_pk_u(attv, attv);
  unsigned c02_pk = 0x32663266u;                    // (0.2, 0.2) f16
  fp16x2 one_pk = as_h2(0x3C003C00u);               // (1.0, 1.0) f16
  const unsigned short* XLu = (const unsigned short*)XL16;
  unsigned ju = (unsigned)j;

  float xrA = XR[(size_t)nA * HDIM + j];
  float xrB = XR[(size_t)nBc * HDIM + j];
  unsigned xr_pkA = cvt_pk_u(xrA, xrA);
  unsigned xr_pkB = cvt_pk_u(xrB, xrB);

  // self-loops (f32 path)
  float xlA = (float)XL16[(size_t)nA * HDIM + j];
  float pA = head_reduce32(lrelu_(xlA + xrA) * attv);
  float exA = __expf(pA);
  float aA0 = exA * xlA, aA1 = 0.f, dA0 = exA, dA1 = 0.f;

  float xlB = (float)XL16[(size_t)nBc * HDIM + j];
  float pB = head_reduce32(lrelu_(xlB + xrB) * attv);
  float exB = __expf(pB);
  float aB0 = exB * xlB, aB1 = 0.f, dB0 = exB, dB1 = 0.f;

  int baseA = row_off[nA], cntA = deg[nA];
  int baseB = hasB ? row_off[nB] : 0;
  int cntB = hasB ? deg[nB] : 0;
  int mA = cntA < 64 ? cntA : 64;
  int mB = cntB < 64 ? cntB : 64;
  int sidxA = (j < mA) ? csr_src[baseA + j] : 0;
  int sidxB = (j < mB) ? csr_src[baseB + j] : 0;
  int ngA = (((mA + 1) >> 1) + 7) >> 3;
  int ngB = (((mB + 1) >> 1) + 7) >> 3;

  unsigned xa[8], xb[8];
  int gA = 0, gB = 0;
  while (gA < ngA || gB < ngB) {
    bool doA = gA < ngA, doB = gB < ngB;
    if (doA) { LOAD8G(xa, sidxA, gA); }
    if (doB) { LOAD8G(xb, sidxB, gB); }
    if (doA) { PROC8G(xa, gA, mA, xr_pkA, aA0, aA1, dA0, dA1); ++gA; }
    if (doB) { PROC8G(xb, gB, mB, xr_pkB, aB0, aB1, dB0, dB1); ++gB; }
  }

  // rare: deg > 64 chunks
  for (int c0 = 64; c0 < cntA; c0 += 64) {
    int m_ = cntA - c0; if (m_ > 64) m_ = 64;
    int sidx = (j < m_) ? csr_src[baseA + c0 + j] : 0;
    int ng = (((m_ + 1) >> 1) + 7) >> 3;
    for (int g = 0; g < ng; ++g) {
      LOAD8G(xa, sidx, g);
      PROC8G(xa, g, m_, xr_pkA, aA0, aA1, dA0, dA1);
    }
  }
  for (int c0 = 64; c0 < cntB; c0 += 64) {
    int m_ = cntB - c0; if (m_ > 64) m_ = 64;
    int sidx = (j < m_) ? csr_src[baseB + c0 + j] : 0;
    int ng = (((m_ + 1) >> 1) + 7) >> 3;
    for (int g = 0; g < ng; ++g) {
      LOAD8G(xb, sidx, g);
      PROC8G(xb, g, m_, xr_pkB, aB0, aB1, dB0, dB1);
    }
  }

  // epilogues
  {
    float acc = aA0 + aA1, den = dA0 + dA1;
    float y = acc / (den + 1e-16f) + gb[j];
    y = y > 0.f ? y : __expf(y) - 1.f;
    float mu = full_reduce64(y) * (1.f / 64.f);
    float d = y - mu;
    float var = full_reduce64(d * d) * (1.f / 64.f);
    Y[(size_t)nA * HDIM + j] = d * rsqrtf(var + 1e-5f) * lng[j] + lnb[j];
  }
  if (hasB) {
    float acc = aB0 + aB1, den = dB0 + dB1;
    float y = acc / (den + 1e-16f) + gb[j];
    y = y > 0.f ? y : __expf(y) - 1.f;
    float mu = full_reduce64(y) * (1.f / 64.f);
    float d = y - mu;
    float var = full_reduce64(d * d) * (1.f / 64.f);
    Y[(size_t)nB * HDIM + j] = d * rsqrtf(var + 1e-5f) * lng[j] + lnb[j];
  }
}

// ======================= k3: Y -> XL2(f16)/XR2(f32) via f16 MFMA =======================
__global__ void __launch_bounds__(256) k3_mfma(const float* __restrict__ Y,
                      const _Float16* __restrict__ Wb, _Float16* __restrict__ XL16,
                      float* __restrict__ XR, int N) {
  __shared__ _Float16 W[128 * GSTR];
  for (int i = threadIdx.x; i < 128 * GSTR / 8; i += 256)
    ((int4*)W)[i] = ((const int4*)Wb)[i];
  __syncthreads();
  int wave = blockIdx.x * 4 + (threadIdx.x >> 6);
  int nwaves = gridDim.x * 4;
  int lane = threadIdx.x & 63;
  int c = lane & 15, q = lane >> 4;
  for (int n0 = wave * 16; n0 < N; n0 += nwaves * 16) {
    bool okrow = (n0 + c) < N;
    const float* yrow = Y + (size_t)(n0 + c) * HDIM + q * 8;
    float4 v0 = {0,0,0,0}, v1 = {0,0,0,0}, v2 = {0,0,0,0}, v3 = {0,0,0,0};
    if (okrow) {
      v0 = *(const float4*)(yrow);
      v1 = *(const float4*)(yrow + 4);
      v2 = *(const float4*)(yrow + 32);
      v3 = *(const float4*)(yrow + 36);
    }
    half8 a0, a1;
    a0[0]=(_Float16)v0.x; a0[1]=(_Float16)v0.y; a0[2]=(_Float16)v0.z; a0[3]=(_Float16)v0.w;
    a0[4]=(_Float16)v1.x; a0[5]=(_Float16)v1.y; a0[6]=(_Float16)v1.z; a0[7]=(_Float16)v1.w;
    a1[0]=(_Float16)v2.x; a1[1]=(_Float16)v2.y; a1[2]=(_Float16)v2.z; a1[3]=(_Float16)v2.w;
    a1[4]=(_Float16)v3.x; a1[5]=(_Float16)v3.y; a1[6]=(_Float16)v3.z; a1[7]=(_Float16)v3.w;

    f32x4 acc[8];
#pragma unroll
    for (int t = 0; t < 8; ++t) acc[t] = (f32x4){0.f, 0.f, 0.f, 0.f};
#pragma unroll
    for (int t = 0; t < 8; ++t) {
      half8 b0 = *(const half8*)(&W[(t * 16 + c) * GSTR + q * 8]);
      half8 b1 = *(const half8*)(&W[(t * 16 + c) * GSTR + 32 + q * 8]);
      acc[t] = __builtin_amdgcn_mfma_f32_16x16x32_f16(a0, b0, acc[t], 0, 0, 0);
      acc[t] = __builtin_amdgcn_mfma_f32_16x16x32_f16(a1, b1, acc[t], 0, 0, 0);
    }
#pragma unroll
    for (int t = 0; t < 4; ++t) {
#pragma unroll
      for (int i = 0; i < 4; ++i) {
        int n = n0 + q * 4 + i;
        if (n < N) {
          XL16[(size_t)n * HDIM + t * 16 + c] = (_Float16)acc[t][i];
          XR[(size_t)n * HDIM + t * 16 + c] = acc[t + 4][i];
        }
      }
    }
  }
}

// ======================= k5: GRU via f16 MFMA + heads =======================
__global__ void __launch_bounds__(256) k5_gru_mfma(const float* __restrict__ Y,
                       const _Float16* __restrict__ Wt,
                       const float* __restrict__ bi, const float* __restrict__ bh,
                       const float* __restrict__ huW, const float* __restrict__ hub,
                       const float* __restrict__ hfW, const float* __restrict__ hfb,
                       const float* __restrict__ hoW, const float* __restrict__ hob,
                       const float* __restrict__ hcW, const float* __restrict__ hcb,
                       float* __restrict__ out, int N) {
  __shared__ _Float16 W[192 * GSTR];
  __shared__ float BS[192];
  __shared__ float BHN[64];
  for (int i = threadIdx.x; i < 192 * GSTR / 8; i += 256)
    ((int4*)W)[i] = ((const int4*)Wt)[i];
  for (int i = threadIdx.x; i < 192; i += 256) BS[i] = bi[i] + (i < 128 ? bh[i] : 0.f);
  for (int i = threadIdx.x; i < 64; i += 256) BHN[i] = bh[128 + i];
  __syncthreads();

  int wave = blockIdx.x * 4 + (threadIdx.x >> 6);
  int nwaves = gridDim.x * 4;
  int lane = threadIdx.x & 63;
  int c = lane & 15, q = lane >> 4;

  float hu_[4], hf_[4], ho_[4], hc_[4];
#pragma unroll
  for (int t = 0; t < 4; ++t) {
    hu_[t] = huW[t * 16 + c];
    hf_[t] = hfW[t * 16 + c];
    ho_[t] = hoW[t * 16 + c];
    hc_[t] = hcW[t * 16 + c];
  }
  float hub0 = hub[0], hfb0 = hfb[0], hob0 = hob[0], hcb0 = hcb[0];

  for (int n0 = wave * 16; n0 < N; n0 += nwaves * 16) {
    bool okrow = (n0 + c) < N;
    const float* yrow = Y + (size_t)(n0 + c) * HDIM + q * 8;
    float4 v0 = {0,0,0,0}, v1 = {0,0,0,0}, v2 = {0,0,0,0}, v3 = {0,0,0,0};
    if (okrow) {
      v0 = *(const float4*)(yrow);
      v1 = *(const float4*)(yrow + 4);
      v2 = *(const float4*)(yrow + 32);
      v3 = *(const float4*)(yrow + 36);
    }
    half8 a0, a1;
    a0[0]=(_Float16)v0.x; a0[1]=(_Float16)v0.y; a0[2]=(_Float16)v0.z; a0[3]=(_Float16)v0.w;
    a0[4]=(_Float16)v1.x; a0[5]=(_Float16)v1.y; a0[6]=(_Float16)v1.z; a0[7]=(_Float16)v1.w;
    a1[0]=(_Float16)v2.x; a1[1]=(_Float16)v2.y; a1[2]=(_Float16)v2.z; a1[3]=(_Float16)v2.w;
    a1[4]=(_Float16)v3.x; a1[5]=(_Float16)v3.y; a1[6]=(_Float16)v3.z; a1[7]=(_Float16)v3.w;

    f32x4 acc[12];
#pragma unroll
    for (int t = 0; t < 12; ++t) acc[t] = (f32x4){0.f, 0.f, 0.f, 0.f};
#pragma unroll
    for (int t = 0; t < 12; ++t) {
      half8 b0 = *(const half8*)(&W[(t * 16 + c) * GSTR + q * 8]);
      half8 b1 = *(const half8*)(&W[(t * 16 + c) * GSTR + 32 + q * 8]);
      acc[t] = __builtin_amdgcn_mfma_f32_16x16x32_f16(a0, b0, acc[t], 0, 0, 0);
      acc[t] = __builtin_amdgcn_mfma_f32_16x16x32_f16(a1, b1, acc[t], 0, 0, 0);
    }

    float hv[4][4];
#pragma unroll
    for (int t = 0; t < 4; ++t) {
      int cr = t * 16 + c;
      float bsr = BS[cr], bsz = BS[64 + cr], bsn = BS[128 + cr], bhn = BHN[cr];
#pragma unroll
      for (int i = 0; i < 4; ++i) {
        float r = sigmoidf_(acc[t][i] + bsr);
        float z = sigmoidf_(acc[t + 4][i] + bsz);
        float nn = tanhf(acc[t + 8][i] + bsn + r * bhn);
        hv[t][i] = (1.f - z) * nn;
      }
    }
#pragma unroll
    for (int i = 0; i < 4; ++i) {
      float pu = 0.f, pf = 0.f, po = 0.f, pc = 0.f;
#pragma unroll
      for (int t = 0; t < 4; ++t) {
        pu += hv[t][i] * hu_[t];
        pf += hv[t][i] * hf_[t];
        po += hv[t][i] * ho_[t];
        pc += hv[t][i] * hc_[t];
      }
      pu = reduce16(pu); pf = reduce16(pf); po = reduce16(po); pc = reduce16(pc);
      int n = n0 + q * 4 + i;
      if (n < N) {
        if (c == 0) out[n]         = sigmoidf_(pu + hub0);
        if (c == 1) out[N + n]     = sigmoidf_(pf + hfb0);
        if (c == 2) out[2 * N + n] = fmaxf(po + hob0, 0.f);
        if (c == 3) out[3 * N + n] = sigmoidf_(pc + hcb0);
      }
    }
  }
}

// ======================= launch =======================
extern "C" void kernel_launch(void* const* d_in, const int* in_sizes, int n_in,
                              void* d_out, int out_size, void* d_ws, size_t ws_size,
                              hipStream_t stream) {
  const float* nf    = (const float*)d_in[0];
  const int*   ei    = (const int*)d_in[1];
  const float* projW = (const float*)d_in[2];
  const float* projB = (const float*)d_in[3];
  const float* g1Wl  = (const float*)d_in[4];
  const float* g1Wr  = (const float*)d_in[5];
  const float* g1att = (const float*)d_in[6];
  const float* g1b   = (const float*)d_in[7];
  const float* g2Wl  = (const float*)d_in[8];
  const float* g2Wr  = (const float*)d_in[9];
  const float* g2att = (const float*)d_in[10];
  const float* g2b   = (const float*)d_in[11];
  const float* ln1g  = (const float*)d_in[12];
  const float* ln1b  = (const float*)d_in[13];
  const float* ln2g  = (const float*)d_in[14];
  const float* ln2b  = (const float*)d_in[15];
  const float* gruWi = (const float*)d_in[16];
  // d_in[17] = gru_Wh, unused (h0 = 0)
  const float* gruBi = (const float*)d_in[18];
  const float* gruBh = (const float*)d_in[19];
  const float* huW = (const float*)d_in[20];
  const float* hub = (const float*)d_in[21];
  const float* hfW = (const float*)d_in[22];
  const float* hfb = (const float*)d_in[23];
  const float* hoW = (const float*)d_in[24];
  const float* hob = (const float*)d_in[25];
  const float* hcW = (const float*)d_in[26];
  const float* hcb = (const float*)d_in[27];
  float* out = (float*)d_out;

  const int N = in_sizes[0] / NDIM;
  const int E = in_sizes[1] / 2;
  int bsh = 8;
  while (((N - 1) >> bsh) >= NB) ++bsh;
  const int nbu = (N + (1 << bsh) - 1) >> bsh;
  const int cap = (E + nbu - 1) / nbu + 768;   // +12 sigma over Poisson mean

  char* ws = (char*)d_ws;
  size_t off = 0;
  auto carve = [&](size_t bytes) { void* p = ws + off; off += (bytes + 255) & ~size_t(255); return p; };
  _Float16*  XL16    = (_Float16*)carve(sizeof(_Float16) * N * HDIM);
  float*     XR      = (float*)carve(sizeof(float) * N * HDIM);
  float*     Y       = (float*)carve(sizeof(float) * N * HDIM);
  long long* pairs   = (long long*)carve(sizeof(long long) * (size_t)nbu * cap);
  int*       csr_src = (int*)carve(sizeof(int) * (size_t)nbu * cap);
  int*       deg     = (int*)carve(sizeof(int) * N);
  int*       row_off = (int*)carve(sizeof(int) * N);
  int*       bcur    = (int*)carve(sizeof(int) * NB);
  float*     Wfl     = (float*)carve(sizeof(float) * NDIM * HDIM);
  float*     Wfr     = (float*)carve(sizeof(float) * NDIM * HDIM);
  float*     bfl     = (float*)carve(sizeof(float) * HDIM);
  float*     bfr     = (float*)carve(sizeof(float) * HDIM);
  _Float16*  Wt      = (_Float16*)carve(sizeof(_Float16) * 192 * GSTR);
  _Float16*  Wb      = (_Float16*)carve(sizeof(_Float16) * 128 * GSTR);

  const int BLK = 256;
  dim3 b(BLK);
  dim3 gridWaveN((N + 3) / 4);
  dim3 gridAgg(((N + 1) / 2 + 3) / 4);           // 2 nodes per wave
  dim3 gridBin((E + BLK * EPB - 1) / (BLK * EPB));

  // ---- weight prep + bcur init (merged) ----
  k_wprep<<<dim3(86), b, 0, stream>>>(projW, projB, g1Wl, g1Wr, gruWi, g2Wl, g2Wr,
                                      Wfl, Wfr, bfl, bfr, Wt, Wb, bcur, cap);

  // ---- CSR build (direct-binned) ----
  k_bin<<<gridBin, b, 0, stream>>>(ei, pairs, bcur, E, bsh);
  k_csr<<<dim3(nbu), b, 0, stream>>>(pairs, bcur, row_off, deg, csr_src, N, bsh, cap);

  // ---- pipeline ----
  k1_xlxr<<<gridWaveN, b, 0, stream>>>(nf, Wfl, Wfr, bfl, bfr, XL16, XR, N);
  k_agg<<<gridAgg, b, 0, stream>>>(csr_src, row_off, deg, XL16, XR, g1att, g1b, ln1g, ln1b, Y, N);
  k3_mfma<<<dim3(800), b, 0, stream>>>(Y, Wb, XL16, XR, N);
  k_agg<<<gridAgg, b, 0, stream>>>(csr_src, row_off, deg, XL16, XR, g2att, g2b, ln2g, ln2b, Y, N);
  k5_gru_mfma<<<dim3(800), b, 0, stream>>>(Y, Wt, gruBi, gruBh,
                                           huW, hub, hfW, hfb, hoW, hob, hcW, hcb, out, N);
}

// Round 14
// 362.954 us; speedup vs baseline: 1.1630x; 1.1630x over previous
//
#include <hip/hip_runtime.h>

#define NDIM 14
#define HDIM 64
#define NB 512         // scatter bucket slots (nbu <= NB used)
#define EPB 16         // edges per thread in k_bin
#define GSTR 72        // padded col stride (halfs) for LDS-staged f16 weights

typedef __attribute__((ext_vector_type(8))) _Float16 half8;
typedef __attribute__((ext_vector_type(2))) __fp16 fp16x2;   // builtin interop type
typedef __attribute__((ext_vector_type(4))) float f32x4;

static __device__ __forceinline__ float sigmoidf_(float x) { return 1.f / (1.f + __expf(-x)); }
static __device__ __forceinline__ float lrelu_(float x) { return x > 0.f ? x : 0.2f * x; }

static __device__ __forceinline__ float readlane_f(float x, int lane) {
  return __int_as_float(__builtin_amdgcn_readlane(__float_as_int(x), lane));
}

template <int CTRL>
static __device__ __forceinline__ float dpp_add_f(float x) {
  int v = __builtin_amdgcn_update_dpp(0, __float_as_int(x), CTRL, 0xF, 0xF, true);
  return x + __int_as_float(v);
}

// f32 sum over each 16-lane DPP row
static __device__ __forceinline__ float reduce16(float p) {
  p = dpp_add_f<0xB1>(p);
  p = dpp_add_f<0x4E>(p);
  p = dpp_add_f<0x141>(p);
  p = dpp_add_f<0x140>(p);
  return p;
}
// f32 sum within each 32-lane half
static __device__ __forceinline__ float head_reduce32(float p) {
  p = reduce16(p);
  p += __int_as_float(__builtin_amdgcn_ds_swizzle(__float_as_int(p), 0x401F));
  return p;
}
static __device__ __forceinline__ float full_reduce64(float p) {
  p = head_reduce32(p);
  p += __shfl_xor(p, 32, 64);
  return p;
}

// ---- packed f16 helpers ----
static __device__ __forceinline__ unsigned pk_add(unsigned a, unsigned b) {
  unsigned d; asm("v_pk_add_f16 %0, %1, %2" : "=v"(d) : "v"(a), "v"(b)); return d;
}
static __device__ __forceinline__ unsigned pk_mul(unsigned a, unsigned b) {
  unsigned d; asm("v_pk_mul_f16 %0, %1, %2" : "=v"(d) : "v"(a), "v"(b)); return d;
}
static __device__ __forceinline__ unsigned pk_max(unsigned a, unsigned b) {
  unsigned d; asm("v_pk_max_f16 %0, %1, %2" : "=v"(d) : "v"(a), "v"(b)); return d;
}
static __device__ __forceinline__ unsigned cvt_pk_u(float a, float b) {
  fp16x2 h = __builtin_amdgcn_cvt_pkrtz(a, b);
  unsigned u; __builtin_memcpy(&u, &h, 4); return u;
}
static __device__ __forceinline__ fp16x2 as_h2(unsigned u) {
  fp16x2 h; __builtin_memcpy(&h, &u, 4); return h;
}
static __device__ __forceinline__ float cvt_lo(unsigned u) {
  float r; asm("v_cvt_f32_f16 %0, %1" : "=v"(r) : "v"(u)); return r;
}
template <int CTRL>
static __device__ __forceinline__ unsigned pk_dpp_add(unsigned x) {
  unsigned v = (unsigned)__builtin_amdgcn_update_dpp(0, (int)x, CTRL, 0xF, 0xF, true);
  return pk_add(x, v);
}
// packed f16 sum within each 32-lane half: 4 DPP + 1 swizzle
static __device__ __forceinline__ unsigned pk_reduce32(unsigned p) {
  p = pk_dpp_add<0xB1>(p);     // xor1
  p = pk_dpp_add<0x4E>(p);     // xor2
  p = pk_dpp_add<0x141>(p);    // 8-group mirror
  p = pk_dpp_add<0x140>(p);    // 16-group mirror
  p = pk_add(p, (unsigned)__builtin_amdgcn_ds_swizzle((int)p, 0x401F)); // xor16
  return p;
}

// ======================= CSR build (direct-binned, padded buckets, 32-bit pairs) =======================
// pair encoding: (dst_local << 17) | src   [valid: src < 2^17, bsh <= 15]
__global__ void __launch_bounds__(256) k_bin(const int* __restrict__ ei,
                      unsigned* __restrict__ pairs, int* __restrict__ bucket_cur,
                      int E, int bsh) {
  __shared__ int h[NB];
  __shared__ int gb[NB];
  int t = threadIdx.x;
  for (int i = t; i < NB; i += 256) h[i] = 0;
  __syncthreads();
  int c0 = blockIdx.x * (256 * EPB);
  unsigned pr[EPB];
  int br[EPB];
  unsigned lmask = (1u << bsh) - 1u;
#pragma unroll
  for (int i = 0; i < EPB; ++i) {
    int e = c0 + t + i * 256;
    if (e < E) {
      int s = ei[e], d = ei[E + e];
      int b = d >> bsh;
      int r = atomicAdd(&h[b], 1);
      pr[i] = (((unsigned)d & lmask) << 17) | (unsigned)s;
      br[i] = b | (r << 9);
    } else br[i] = -1;
  }
  __syncthreads();
  for (int i = t; i < NB; i += 256)
    if (h[i]) gb[i] = atomicAdd(&bucket_cur[i], h[i]);
  __syncthreads();
#pragma unroll
  for (int i = 0; i < EPB; ++i) {
    if (br[i] >= 0) pairs[gb[br[i] & (NB - 1)] + (br[i] >> 9)] = pr[i];
  }
}

// per-bucket CSR: degree hist + scan + placement in LDS. One block per bucket.
__global__ void __launch_bounds__(256) k_csr(const unsigned* __restrict__ pairs,
                      const int* __restrict__ bcur_final, int* __restrict__ row_off,
                      int* __restrict__ deg, int* __restrict__ csr_src,
                      int N, int bsh, int cap) {
  __shared__ int h[1024];
  __shared__ int cu[1024];
  __shared__ int wtot[4];
  int b = blockIdx.x;
  int node0 = b << bsh;
  int range = 1 << bsh;
  int nr = N - node0; if (nr > range) nr = range;
  if (nr <= 0) return;
  int e0 = b * cap, e1 = bcur_final[b];
  int tid = threadIdx.x;
  for (int i = tid; i < range; i += 256) h[i] = 0;
  __syncthreads();
  for (int e = e0 + tid; e < e1; e += 256)
    atomicAdd(&h[pairs[e] >> 17], 1);
  __syncthreads();
  if (range == 256) {
    int lane = tid & 63, wid = tid >> 6;
    int v = (tid < nr) ? h[tid] : 0;
    int x = v;
#pragma unroll
    for (int m = 1; m <= 32; m <<= 1) {
      int t2 = __shfl_up(x, m, 64);
      if (lane >= m) x += t2;
    }
    if (lane == 63) wtot[wid] = x;
    __syncthreads();
    int woff = 0;
#pragma unroll
    for (int w = 0; w < 4; ++w) woff += (w < wid) ? wtot[w] : 0;
    int excl = woff + x - v;
    if (tid < nr) {
      row_off[node0 + tid] = e0 + excl;
      deg[node0 + tid] = v;
      cu[tid] = excl;
    }
  } else {
    if (tid == 0) {
      int acc = 0;
      for (int i = 0; i < nr; ++i) {
        row_off[node0 + i] = e0 + acc;
        deg[node0 + i] = h[i];
        cu[i] = acc;
        acc += h[i];
      }
    }
  }
  __syncthreads();
  for (int e = e0 + tid; e < e1; e += 256) {
    unsigned pk = pairs[e];
    int dl = (int)(pk >> 17);
    int s = (int)(pk & 0x1FFFFu);
    int p = atomicAdd(&cu[dl], 1);
    csr_src[e0 + p] = s;
  }
}

// ======================= merged weight prep + bcur init =======================
__global__ void k_wprep(const float* __restrict__ projW, const float* __restrict__ projB,
                        const float* __restrict__ Wl1, const float* __restrict__ Wr1,
                        const float* __restrict__ Wi, const float* __restrict__ Wl2,
                        const float* __restrict__ Wr2,
                        float* __restrict__ Wfl, float* __restrict__ Wfr,
                        float* __restrict__ bfl, float* __restrict__ bfr,
                        _Float16* __restrict__ Wt, _Float16* __restrict__ Wb,
                        int* __restrict__ bcur, int cap) {
  int blk = blockIdx.x;
  if (blk < 4) {
    int t = blk * 256 + threadIdx.x;
    int total = (NDIM + 1) * HDIM;
    if (t >= total) return;
    int r = t / HDIM, c = t % HDIM;
    float al = 0.f, ar = 0.f;
    if (r < NDIM) {
      for (int k = 0; k < HDIM; ++k) {
        float w = projW[r * HDIM + k];
        al += w * Wl1[k * HDIM + c];
        ar += w * Wr1[k * HDIM + c];
      }
      Wfl[r * HDIM + c] = al;
      Wfr[r * HDIM + c] = ar;
    } else {
      for (int k = 0; k < HDIM; ++k) {
        float w = projB[k];
        al += w * Wl1[k * HDIM + c];
        ar += w * Wr1[k * HDIM + c];
      }
      bfl[c] = al;
      bfr[c] = ar;
    }
  } else if (blk < 52) {
    int t = (blk - 4) * 256 + threadIdx.x;
    if (t >= 192 * 64) return;
    int col = t / 64, row = t % 64;
    Wt[col * GSTR + row] = (_Float16)Wi[row * 192 + col];
  } else if (blk < 84) {
    int t = (blk - 52) * 256 + threadIdx.x;
    if (t >= 128 * 64) return;
    int col = t >> 6, row = t & 63;
    float v = (col < 64) ? Wl2[row * 64 + col] : Wr2[row * 64 + (col - 64)];
    Wb[col * GSTR + row] = (_Float16)v;
  } else {
    int i = (blk - 84) * 256 + threadIdx.x;
    if (i < NB) bcur[i] = i * cap;
  }
}

// ======================= k1: XL1(f16)/XR1(f16) from node features =======================
__global__ void k1_xlxr(const float* __restrict__ nf, const float* __restrict__ Wfl,
                        const float* __restrict__ Wfr, const float* __restrict__ bfl,
                        const float* __restrict__ bfr, _Float16* __restrict__ XL16,
                        _Float16* __restrict__ XR16, int N) {
  int n = blockIdx.x * (blockDim.x >> 6) + (threadIdx.x >> 6);
  int j = threadIdx.x & 63;
  if (n >= N) return;
  float nfv = (j < NDIM) ? nf[n * NDIM + j] : 0.f;
  float al = bfl[j], ar = bfr[j];
#pragma unroll
  for (int k = 0; k < NDIM; ++k) {
    float xk = readlane_f(nfv, k);
    al += xk * Wfl[k * HDIM + j];
    ar += xk * Wfr[k * HDIM + j];
  }
  XL16[n * HDIM + j] = (_Float16)al;
  XR16[n * HDIM + j] = (_Float16)ar;
}

// ======================= k_agg: packed-f16 pull-aggregate + softmax + ELU + LN =======================
__global__ void k_agg(const int* __restrict__ csr_src, const int* __restrict__ row_off,
                      const int* __restrict__ deg, const _Float16* __restrict__ XL16,
                      const _Float16* __restrict__ XR16, const float* __restrict__ att,
                      const float* __restrict__ gb, const float* __restrict__ lng,
                      const float* __restrict__ lnb, float* __restrict__ Y, int N) {
  int n = blockIdx.x * (blockDim.x >> 6) + (threadIdx.x >> 6);
  int j = threadIdx.x & 63;
  if (n >= N) return;
  float xr = (float)XR16[(size_t)n * HDIM + j];
  float attv = att[j];
  unsigned xr_pk  = cvt_pk_u(xr, xr);
  unsigned att_pk = cvt_pk_u(attv, attv);
  unsigned c02_pk = 0x32663266u;                    // (0.2, 0.2) f16
  fp16x2 one_pk = as_h2(0x3C003C00u);               // (1.0, 1.0) f16
  const unsigned short* XLu = (const unsigned short*)XL16;
  unsigned ju = (unsigned)j;

  // self-loop (f32 path)
  float xl = (float)XL16[(size_t)n * HDIM + j];
  float p = head_reduce32(lrelu_(xl + xr) * attv);
  float ex = __expf(p);
  float acc0 = ex * xl, acc1 = 0.f;
  float den0 = ex, den1 = 0.f;

  int base = row_off[n], cnt = deg[n];
  for (int c0 = 0; c0 < cnt; c0 += 64) {
    int m_ = cnt - c0; if (m_ > 64) m_ = 64;
    int sidx = (j < m_) ? csr_src[base + c0 + j] : 0;
    int npairs = m_ >> 1;
    int pp = 0;
    // ---- full 8-pair groups, unmasked ----
    for (; pp + 8 <= npairs; pp += 8) {
      unsigned x[8];
#pragma unroll
      for (int u = 0; u < 8; ++u) {
        int sa = __builtin_amdgcn_readlane(sidx, 2 * (pp + u));
        int sb = __builtin_amdgcn_readlane(sidx, 2 * (pp + u) + 1);
        unsigned ua = XLu[((unsigned)sa << 6) + ju];
        unsigned ub = XLu[((unsigned)sb << 6) + ju];
        x[u] = __builtin_amdgcn_perm(ub, ua, 0x05040100u);
      }
#pragma unroll
      for (int u = 0; u < 8; ++u) {
        unsigned t = pk_add(x[u], xr_pk);
        unsigned lr = pk_max(t, pk_mul(t, c02_pk));
        unsigned sc = pk_mul(lr, att_pk);
        sc = pk_reduce32(sc);
        float s_a = cvt_lo(sc), s_b = cvt_lo(sc >> 16);
        float e_a = __expf(s_a), e_b = __expf(s_b);
        fp16x2 exk = __builtin_amdgcn_cvt_pkrtz(e_a, e_b);
        if (u & 1) {
          acc1 = __builtin_amdgcn_fdot2(as_h2(x[u]), exk, acc1, false);
          den1 = __builtin_amdgcn_fdot2(exk, one_pk, den1, false);
        } else {
          acc0 = __builtin_amdgcn_fdot2(as_h2(x[u]), exk, acc0, false);
          den0 = __builtin_amdgcn_fdot2(exk, one_pk, den0, false);
        }
      }
    }
    // ---- remaining pairs ----
    for (; pp < npairs; ++pp) {
      int sa = __builtin_amdgcn_readlane(sidx, 2 * pp);
      int sb = __builtin_amdgcn_readlane(sidx, 2 * pp + 1);
      unsigned ua = XLu[((unsigned)sa << 6) + ju];
      unsigned ub = XLu[((unsigned)sb << 6) + ju];
      unsigned xu = __builtin_amdgcn_perm(ub, ua, 0x05040100u);
      unsigned t = pk_add(xu, xr_pk);
      unsigned lr = pk_max(t, pk_mul(t, c02_pk));
      unsigned sc = pk_mul(lr, att_pk);
      sc = pk_reduce32(sc);
      float s_a = cvt_lo(sc), s_b = cvt_lo(sc >> 16);
      float e_a = __expf(s_a), e_b = __expf(s_b);
      fp16x2 exk = __builtin_amdgcn_cvt_pkrtz(e_a, e_b);
      acc0 = __builtin_amdgcn_fdot2(as_h2(xu), exk, acc0, false);
      den0 = __builtin_amdgcn_fdot2(exk, one_pk, den0, false);
    }
    if (m_ & 1) {   // odd edge, f32 path
      int s = __builtin_amdgcn_readlane(sidx, m_ - 1);
      float xls = (float)XL16[(size_t)s * HDIM + j];
      float pq = head_reduce32(lrelu_(xls + xr) * attv);
      float ee = __expf(pq);
      acc0 += ee * xls;
      den0 += ee;
    }
  }

  float acc = acc0 + acc1;
  float den = den0 + den1;
  float y = acc / (den + 1e-16f) + gb[j];
  y = y > 0.f ? y : __expf(y) - 1.f;
  float mu = full_reduce64(y) * (1.f / 64.f);
  float d = y - mu;
  float var = full_reduce64(d * d) * (1.f / 64.f);
  Y[n * HDIM + j] = d * rsqrtf(var + 1e-5f) * lng[j] + lnb[j];
}

// ======================= k3: Y -> XL2(f16)/XR2(f16) via f16 MFMA =======================
__global__ void __launch_bounds__(256) k3_mfma(const float* __restrict__ Y,
                      const _Float16* __restrict__ Wb, _Float16* __restrict__ XL16,
                      _Float16* __restrict__ XR16, int N) {
  __shared__ _Float16 W[128 * GSTR];
  for (int i = threadIdx.x; i < 128 * GSTR / 8; i += 256)
    ((int4*)W)[i] = ((const int4*)Wb)[i];
  __syncthreads();
  int wave = blockIdx.x * 4 + (threadIdx.x >> 6);
  int nwaves = gridDim.x * 4;
  int lane = threadIdx.x & 63;
  int c = lane & 15, q = lane >> 4;
  for (int n0 = wave * 16; n0 < N; n0 += nwaves * 16) {
    bool okrow = (n0 + c) < N;
    const float* yrow = Y + (size_t)(n0 + c) * HDIM + q * 8;
    float4 v0 = {0,0,0,0}, v1 = {0,0,0,0}, v2 = {0,0,0,0}, v3 = {0,0,0,0};
    if (okrow) {
      v0 = *(const float4*)(yrow);
      v1 = *(const float4*)(yrow + 4);
      v2 = *(const float4*)(yrow + 32);
      v3 = *(const float4*)(yrow + 36);
    }
    half8 a0, a1;
    a0[0]=(_Float16)v0.x; a0[1]=(_Float16)v0.y; a0[2]=(_Float16)v0.z; a0[3]=(_Float16)v0.w;
    a0[4]=(_Float16)v1.x; a0[5]=(_Float16)v1.y; a0[6]=(_Float16)v1.z; a0[7]=(_Float16)v1.w;
    a1[0]=(_Float16)v2.x; a1[1]=(_Float16)v2.y; a1[2]=(_Float16)v2.z; a1[3]=(_Float16)v2.w;
    a1[4]=(_Float16)v3.x; a1[5]=(_Float16)v3.y; a1[6]=(_Float16)v3.z; a1[7]=(_Float16)v3.w;

    f32x4 acc[8];
#pragma unroll
    for (int t = 0; t < 8; ++t) acc[t] = (f32x4){0.f, 0.f, 0.f, 0.f};
#pragma unroll
    for (int t = 0; t < 8; ++t) {
      half8 b0 = *(const half8*)(&W[(t * 16 + c) * GSTR + q * 8]);
      half8 b1 = *(const half8*)(&W[(t * 16 + c) * GSTR + 32 + q * 8]);
      acc[t] = __builtin_amdgcn_mfma_f32_16x16x32_f16(a0, b0, acc[t], 0, 0, 0);
      acc[t] = __builtin_amdgcn_mfma_f32_16x16x32_f16(a1, b1, acc[t], 0, 0, 0);
    }
#pragma unroll
    for (int t = 0; t < 4; ++t) {
#pragma unroll
      for (int i = 0; i < 4; ++i) {
        int n = n0 + q * 4 + i;
        if (n < N) {
          XL16[(size_t)n * HDIM + t * 16 + c] = (_Float16)acc[t][i];
          XR16[(size_t)n * HDIM + t * 16 + c] = (_Float16)acc[t + 4][i];
        }
      }
    }
  }
}

// ======================= k5: GRU via f16 MFMA + heads =======================
__global__ void __launch_bounds__(256) k5_gru_mfma(const float* __restrict__ Y,
                       const _Float16* __restrict__ Wt,
                       const float* __restrict__ bi, const float* __restrict__ bh,
                       const float* __restrict__ huW, const float* __restrict__ hub,
                       const float* __restrict__ hfW, const float* __restrict__ hfb,
                       const float* __restrict__ hoW, const float* __restrict__ hob,
                       const float* __restrict__ hcW, const float* __restrict__ hcb,
                       float* __restrict__ out, int N) {
  __shared__ _Float16 W[192 * GSTR];
  __shared__ float BS[192];
  __shared__ float BHN[64];
  for (int i = threadIdx.x; i < 192 * GSTR / 8; i += 256)
    ((int4*)W)[i] = ((const int4*)Wt)[i];
  for (int i = threadIdx.x; i < 192; i += 256) BS[i] = bi[i] + (i < 128 ? bh[i] : 0.f);
  for (int i = threadIdx.x; i < 64; i += 256) BHN[i] = bh[128 + i];
  __syncthreads();

  int wave = blockIdx.x * 4 + (threadIdx.x >> 6);
  int nwaves = gridDim.x * 4;
  int lane = threadIdx.x & 63;
  int c = lane & 15, q = lane >> 4;

  float hu_[4], hf_[4], ho_[4], hc_[4];
#pragma unroll
  for (int t = 0; t < 4; ++t) {
    hu_[t] = huW[t * 16 + c];
    hf_[t] = hfW[t * 16 + c];
    ho_[t] = hoW[t * 16 + c];
    hc_[t] = hcW[t * 16 + c];
  }
  float hub0 = hub[0], hfb0 = hfb[0], hob0 = hob[0], hcb0 = hcb[0];

  for (int n0 = wave * 16; n0 < N; n0 += nwaves * 16) {
    bool okrow = (n0 + c) < N;
    const float* yrow = Y + (size_t)(n0 + c) * HDIM + q * 8;
    float4 v0 = {0,0,0,0}, v1 = {0,0,0,0}, v2 = {0,0,0,0}, v3 = {0,0,0,0};
    if (okrow) {
      v0 = *(const float4*)(yrow);
      v1 = *(const float4*)(yrow + 4);
      v2 = *(const float4*)(yrow + 32);
      v3 = *(const float4*)(yrow + 36);
    }
    half8 a0, a1;
    a0[0]=(_Float16)v0.x; a0[1]=(_Float16)v0.y; a0[2]=(_Float16)v0.z; a0[3]=(_Float16)v0.w;
    a0[4]=(_Float16)v1.x; a0[5]=(_Float16)v1.y; a0[6]=(_Float16)v1.z; a0[7]=(_Float16)v1.w;
    a1[0]=(_Float16)v2.x; a1[1]=(_Float16)v2.y; a1[2]=(_Float16)v2.z; a1[3]=(_Float16)v2.w;
    a1[4]=(_Float16)v3.x; a1[5]=(_Float16)v3.y; a1[6]=(_Float16)v3.z; a1[7]=(_Float16)v3.w;

    f32x4 acc[12];
#pragma unroll
    for (int t = 0; t < 12; ++t) acc[t] = (f32x4){0.f, 0.f, 0.f, 0.f};
#pragma unroll
    for (int t = 0; t < 12; ++t) {
      half8 b0 = *(const half8*)(&W[(t * 16 + c) * GSTR + q * 8]);
      half8 b1 = *(const half8*)(&W[(t * 16 + c) * GSTR + 32 + q * 8]);
      acc[t] = __builtin_amdgcn_mfma_f32_16x16x32_f16(a0, b0, acc[t], 0, 0, 0);
      acc[t] = __builtin_amdgcn_mfma_f32_16x16x32_f16(a1, b1, acc[t], 0, 0, 0);
    }

    float hv[4][4];
#pragma unroll
    for (int t = 0; t < 4; ++t) {
      int cr = t * 16 + c;
      float bsr = BS[cr], bsz = BS[64 + cr], bsn = BS[128 + cr], bhn = BHN[cr];
#pragma unroll
      for (int i = 0; i < 4; ++i) {
        float r = sigmoidf_(acc[t][i] + bsr);
        float z = sigmoidf_(acc[t + 4][i] + bsz);
        float nn = tanhf(acc[t + 8][i] + bsn + r * bhn);
        hv[t][i] = (1.f - z) * nn;
      }
    }
#pragma unroll
    for (int i = 0; i < 4; ++i) {
      float pu = 0.f, pf = 0.f, po = 0.f, pc = 0.f;
#pragma unroll
      for (int t = 0; t < 4; ++t) {
        pu += hv[t][i] * hu_[t];
        pf += hv[t][i] * hf_[t];
        po += hv[t][i] * ho_[t];
        pc += hv[t][i] * hc_[t];
      }
      pu = reduce16(pu); pf = reduce16(pf); po = reduce16(po); pc = reduce16(pc);
      int n = n0 + q * 4 + i;
      if (n < N) {
        if (c == 0) out[n]         = sigmoidf_(pu + hub0);
        if (c == 1) out[N + n]     = sigmoidf_(pf + hfb0);
        if (c == 2) out[2 * N + n] = fmaxf(po + hob0, 0.f);
        if (c == 3) out[3 * N + n] = sigmoidf_(pc + hcb0);
      }
    }
  }
}

// ======================= launch =======================
extern "C" void kernel_launch(void* const* d_in, const int* in_sizes, int n_in,
                              void* d_out, int out_size, void* d_ws, size_t ws_size,
                              hipStream_t stream) {
  const float* nf    = (const float*)d_in[0];
  const int*   ei    = (const int*)d_in[1];
  const float* projW = (const float*)d_in[2];
  const float* projB = (const float*)d_in[3];
  const float* g1Wl  = (const float*)d_in[4];
  const float* g1Wr  = (const float*)d_in[5];
  const float* g1att = (const float*)d_in[6];
  const float* g1b   = (const float*)d_in[7];
  const float* g2Wl  = (const float*)d_in[8];
  const float* g2Wr  = (const float*)d_in[9];
  const float* g2att = (const float*)d_in[10];
  const float* g2b   = (const float*)d_in[11];
  const float* ln1g  = (const float*)d_in[12];
  const float* ln1b  = (const float*)d_in[13];
  const float* ln2g  = (const float*)d_in[14];
  const float* ln2b  = (const float*)d_in[15];
  const float* gruWi = (const float*)d_in[16];
  // d_in[17] = gru_Wh, unused (h0 = 0)
  const float* gruBi = (const float*)d_in[18];
  const float* gruBh = (const float*)d_in[19];
  const float* huW = (const float*)d_in[20];
  const float* hub = (const float*)d_in[21];
  const float* hfW = (const float*)d_in[22];
  const float* hfb = (const float*)d_in[23];
  const float* hoW = (const float*)d_in[24];
  const float* hob = (const float*)d_in[25];
  const float* hcW = (const float*)d_in[26];
  const float* hcb = (const float*)d_in[27];
  float* out = (float*)d_out;

  const int N = in_sizes[0] / NDIM;
  const int E = in_sizes[1] / 2;
  int bsh = 8;
  while (((N - 1) >> bsh) >= NB) ++bsh;
  const int nbu = (N + (1 << bsh) - 1) >> bsh;
  const int cap = (E + nbu - 1) / nbu + 768;   // +12 sigma over Poisson mean

  char* ws = (char*)d_ws;
  size_t off = 0;
  auto carve = [&](size_t bytes) { void* p = ws + off; off += (bytes + 255) & ~size_t(255); return p; };
  _Float16*  XL16    = (_Float16*)carve(sizeof(_Float16) * N * HDIM);
  _Float16*  XR16    = (_Float16*)carve(sizeof(_Float16) * N * HDIM);
  float*     Y       = (float*)carve(sizeof(float) * N * HDIM);
  unsigned*  pairs   = (unsigned*)carve(sizeof(unsigned) * (size_t)nbu * cap);
  int*       csr_src = (int*)carve(sizeof(int) * (size_t)nbu * cap);
  int*       deg     = (int*)carve(sizeof(int) * N);
  int*       row_off = (int*)carve(sizeof(int) * N);
  int*       bcur    = (int*)carve(sizeof(int) * NB);
  float*     Wfl     = (float*)carve(sizeof(float) * NDIM * HDIM);
  float*     Wfr     = (float*)carve(sizeof(float) * NDIM * HDIM);
  float*     bfl     = (float*)carve(sizeof(float) * HDIM);
  float*     bfr     = (float*)carve(sizeof(float) * HDIM);
  _Float16*  Wt      = (_Float16*)carve(sizeof(_Float16) * 192 * GSTR);
  _Float16*  Wb      = (_Float16*)carve(sizeof(_Float16) * 128 * GSTR);

  const int BLK = 256;
  dim3 b(BLK);
  dim3 gridWaveN((N + 3) / 4);
  dim3 gridBin((E + BLK * EPB - 1) / (BLK * EPB));

  // ---- weight prep + bcur init (merged) ----
  k_wprep<<<dim3(86), b, 0, stream>>>(projW, projB, g1Wl, g1Wr, gruWi, g2Wl, g2Wr,
                                      Wfl, Wfr, bfl, bfr, Wt, Wb, bcur, cap);

  // ---- CSR build (direct-binned, 32-bit pairs) ----
  k_bin<<<gridBin, b, 0, stream>>>(ei, pairs, bcur, E, bsh);
  k_csr<<<dim3(nbu), b, 0, stream>>>(pairs, bcur, row_off, deg, csr_src, N, bsh, cap);

  // ---- pipeline ----
  k1_xlxr<<<gridWaveN, b, 0, stream>>>(nf, Wfl, Wfr, bfl, bfr, XL16, XR16, N);
  k_agg<<<gridWaveN, b, 0, stream>>>(csr_src, row_off, deg, XL16, XR16, g1att, g1b, ln1g, ln1b, Y, N);
  k3_mfma<<<dim3(800), b, 0, stream>>>(Y, Wb, XL16, XR16, N);
  k_agg<<<gridWaveN, b, 0, stream>>>(csr_src, row_off, deg, XL16, XR16, g2att, g2b, ln2g, ln2b, Y, N);
  k5_gru_mfma<<<dim3(800), b, 0, stream>>>(Y, Wt, gruBi, gruBh,
                                           huW, hub, hfW, hfb, hoW, hob, hcW, hcb, out, N);
}

// Round 15
// 345.708 us; speedup vs baseline: 1.2210x; 1.0499x over previous
//
#include <hip/hip_runtime.h>

#define NDIM 14
#define HDIM 64
#define NB 512         // scatter bucket slots (nbu <= NB used)
#define EPB 16         // edges per thread in k_bin
#define GSTR 72        // padded col stride (halfs) for LDS-staged f16 weights

typedef __attribute__((ext_vector_type(8))) _Float16 half8;
typedef __attribute__((ext_vector_type(2))) __fp16 fp16x2;   // builtin interop type
typedef __attribute__((ext_vector_type(4))) float f32x4;

static __device__ __forceinline__ float sigmoidf_(float x) { return 1.f / (1.f + __expf(-x)); }
static __device__ __forceinline__ float lrelu_(float x) { return x > 0.f ? x : 0.2f * x; }

static __device__ __forceinline__ float readlane_f(float x, int lane) {
  return __int_as_float(__builtin_amdgcn_readlane(__float_as_int(x), lane));
}

template <int CTRL>
static __device__ __forceinline__ float dpp_add_f(float x) {
  int v = __builtin_amdgcn_update_dpp(0, __float_as_int(x), CTRL, 0xF, 0xF, true);
  return x + __int_as_float(v);
}

// f32 sum over each 16-lane DPP row
static __device__ __forceinline__ float reduce16(float p) {
  p = dpp_add_f<0xB1>(p);
  p = dpp_add_f<0x4E>(p);
  p = dpp_add_f<0x141>(p);
  p = dpp_add_f<0x140>(p);
  return p;
}
// f32 sum within each 32-lane half
static __device__ __forceinline__ float head_reduce32(float p) {
  p = reduce16(p);
  p += __int_as_float(__builtin_amdgcn_ds_swizzle(__float_as_int(p), 0x401F));
  return p;
}
static __device__ __forceinline__ float full_reduce64(float p) {
  p = head_reduce32(p);
  p += __shfl_xor(p, 32, 64);
  return p;
}

// ---- packed f16 helpers ----
static __device__ __forceinline__ unsigned pk_add(unsigned a, unsigned b) {
  unsigned d; asm("v_pk_add_f16 %0, %1, %2" : "=v"(d) : "v"(a), "v"(b)); return d;
}
static __device__ __forceinline__ unsigned pk_mul(unsigned a, unsigned b) {
  unsigned d; asm("v_pk_mul_f16 %0, %1, %2" : "=v"(d) : "v"(a), "v"(b)); return d;
}
static __device__ __forceinline__ unsigned pk_max(unsigned a, unsigned b) {
  unsigned d; asm("v_pk_max_f16 %0, %1, %2" : "=v"(d) : "v"(a), "v"(b)); return d;
}
static __device__ __forceinline__ unsigned cvt_pk_u(float a, float b) {
  fp16x2 h = __builtin_amdgcn_cvt_pkrtz(a, b);
  unsigned u; __builtin_memcpy(&u, &h, 4); return u;
}
static __device__ __forceinline__ fp16x2 as_h2(unsigned u) {
  fp16x2 h; __builtin_memcpy(&h, &u, 4); return h;
}
static __device__ __forceinline__ float cvt_lo(unsigned u) {
  float r; asm("v_cvt_f32_f16 %0, %1" : "=v"(r) : "v"(u)); return r;
}
template <int CTRL>
static __device__ __forceinline__ unsigned pk_dpp_add(unsigned x) {
  unsigned v = (unsigned)__builtin_amdgcn_update_dpp(0, (int)x, CTRL, 0xF, 0xF, true);
  return pk_add(x, v);
}
// packed f16 sum within each 32-lane half: 4 DPP + 1 swizzle
static __device__ __forceinline__ unsigned pk_reduce32(unsigned p) {
  p = pk_dpp_add<0xB1>(p);     // xor1
  p = pk_dpp_add<0x4E>(p);     // xor2
  p = pk_dpp_add<0x141>(p);    // 8-group mirror
  p = pk_dpp_add<0x140>(p);    // 16-group mirror
  p = pk_add(p, (unsigned)__builtin_amdgcn_ds_swizzle((int)p, 0x401F)); // xor16
  return p;
}

// ======================= D1: k_bin (blocks < nBin) + weight prep (blocks >= nBin) ==============
// pair encoding: (dst_local << 17) | src   [valid: src < 2^17, bsh <= 15]
// bucket_cur holds OFFSETS from bucket base (init 0 by memset).
__global__ void __launch_bounds__(256) k_bin_wprep(const int* __restrict__ ei,
                      unsigned* __restrict__ pairs, int* __restrict__ bucket_cur,
                      int E, int bsh, int cap, int nBin,
                      const float* __restrict__ projW, const float* __restrict__ projB,
                      const float* __restrict__ Wl1, const float* __restrict__ Wr1,
                      const float* __restrict__ Wi, const float* __restrict__ Wl2,
                      const float* __restrict__ Wr2,
                      float* __restrict__ Wfl, float* __restrict__ Wfr,
                      float* __restrict__ bfl, float* __restrict__ bfr,
                      _Float16* __restrict__ Wt, _Float16* __restrict__ Wb) {
  __shared__ int h[NB];
  __shared__ int gb[NB];
  int t = threadIdx.x;
  if ((int)blockIdx.x >= nBin) {
    int blk = blockIdx.x - nBin;
    if (blk < 4) {
      int tt = blk * 256 + t;
      int total = (NDIM + 1) * HDIM;
      if (tt >= total) return;
      int r = tt / HDIM, c = tt % HDIM;
      float al = 0.f, ar = 0.f;
      if (r < NDIM) {
        for (int k = 0; k < HDIM; ++k) {
          float w = projW[r * HDIM + k];
          al += w * Wl1[k * HDIM + c];
          ar += w * Wr1[k * HDIM + c];
        }
        Wfl[r * HDIM + c] = al;
        Wfr[r * HDIM + c] = ar;
      } else {
        for (int k = 0; k < HDIM; ++k) {
          float w = projB[k];
          al += w * Wl1[k * HDIM + c];
          ar += w * Wr1[k * HDIM + c];
        }
        bfl[c] = al;
        bfr[c] = ar;
      }
    } else if (blk < 52) {
      int tt = (blk - 4) * 256 + t;
      if (tt >= 192 * 64) return;
      int col = tt / 64, row = tt % 64;
      Wt[col * GSTR + row] = (_Float16)Wi[row * 192 + col];
    } else {
      int tt = (blk - 52) * 256 + t;
      if (tt >= 128 * 64) return;
      int col = tt >> 6, row = tt & 63;
      float v = (col < 64) ? Wl2[row * 64 + col] : Wr2[row * 64 + (col - 64)];
      Wb[col * GSTR + row] = (_Float16)v;
    }
    return;
  }
  // ---- bin path ----
  for (int i = t; i < NB; i += 256) h[i] = 0;
  __syncthreads();
  int c0 = blockIdx.x * (256 * EPB);
  unsigned pr[EPB];
  int br[EPB];
  unsigned lmask = (1u << bsh) - 1u;
#pragma unroll
  for (int i = 0; i < EPB; ++i) {
    int e = c0 + t + i * 256;
    if (e < E) {
      int s = ei[e], d = ei[E + e];
      int b = d >> bsh;
      int r = atomicAdd(&h[b], 1);
      pr[i] = (((unsigned)d & lmask) << 17) | (unsigned)s;
      br[i] = b | (r << 9);
    } else br[i] = -1;
  }
  __syncthreads();
  for (int i = t; i < NB; i += 256)
    if (h[i]) gb[i] = atomicAdd(&bucket_cur[i], h[i]);
  __syncthreads();
#pragma unroll
  for (int i = 0; i < EPB; ++i) {
    if (br[i] >= 0) {
      int b = br[i] & (NB - 1);
      pairs[b * cap + gb[b] + (br[i] >> 9)] = pr[i];
    }
  }
}

// ======================= D2: k_csr (blocks < nbu) + k1 (blocks >= nbu) =======================
__global__ void __launch_bounds__(256) k_csr_k1(const unsigned* __restrict__ pairs,
                      const int* __restrict__ bcur_final, int* __restrict__ row_off,
                      int* __restrict__ deg, int* __restrict__ csr_src,
                      int N, int bsh, int cap, int nbu,
                      const float* __restrict__ nf, const float* __restrict__ Wfl,
                      const float* __restrict__ Wfr, const float* __restrict__ bfl,
                      const float* __restrict__ bfr, _Float16* __restrict__ XL16,
                      _Float16* __restrict__ XR16) {
  __shared__ int h[1024];
  __shared__ int cu[1024];
  __shared__ int wtot[4];
  int tid = threadIdx.x;
  if ((int)blockIdx.x >= nbu) {
    // ---- k1 path: XL1/XR1 from node features ----
    int n = (blockIdx.x - nbu) * 4 + (tid >> 6);
    int j = tid & 63;
    if (n >= N) return;
    float nfv = (j < NDIM) ? nf[n * NDIM + j] : 0.f;
    float al = bfl[j], ar = bfr[j];
#pragma unroll
    for (int k = 0; k < NDIM; ++k) {
      float xk = readlane_f(nfv, k);
      al += xk * Wfl[k * HDIM + j];
      ar += xk * Wfr[k * HDIM + j];
    }
    XL16[n * HDIM + j] = (_Float16)al;
    XR16[n * HDIM + j] = (_Float16)ar;
    return;
  }
  // ---- csr path ----
  int b = blockIdx.x;
  int node0 = b << bsh;
  int range = 1 << bsh;
  int nr = N - node0; if (nr > range) nr = range;
  if (nr <= 0) return;
  int e0 = b * cap, e1 = e0 + bcur_final[b];
  for (int i = tid; i < range; i += 256) h[i] = 0;
  __syncthreads();
  for (int e = e0 + tid; e < e1; e += 256)
    atomicAdd(&h[pairs[e] >> 17], 1);
  __syncthreads();
  if (range == 256) {
    int lane = tid & 63, wid = tid >> 6;
    int v = (tid < nr) ? h[tid] : 0;
    int x = v;
#pragma unroll
    for (int m = 1; m <= 32; m <<= 1) {
      int t2 = __shfl_up(x, m, 64);
      if (lane >= m) x += t2;
    }
    if (lane == 63) wtot[wid] = x;
    __syncthreads();
    int woff = 0;
#pragma unroll
    for (int w = 0; w < 4; ++w) woff += (w < wid) ? wtot[w] : 0;
    int excl = woff + x - v;
    if (tid < nr) {
      row_off[node0 + tid] = e0 + excl;
      deg[node0 + tid] = v;
      cu[tid] = excl;
    }
  } else {
    if (tid == 0) {
      int acc = 0;
      for (int i = 0; i < nr; ++i) {
        row_off[node0 + i] = e0 + acc;
        deg[node0 + i] = h[i];
        cu[i] = acc;
        acc += h[i];
      }
    }
  }
  __syncthreads();
  for (int e = e0 + tid; e < e1; e += 256) {
    unsigned pk = pairs[e];
    int dl = (int)(pk >> 17);
    int s = (int)(pk & 0x1FFFFu);
    int p = atomicAdd(&cu[dl], 1);
    csr_src[e0 + p] = s;
  }
}

// ======================= k_agg: packed-f16 pull-aggregate + softmax + ELU + LN =======================
__global__ void k_agg(const int* __restrict__ csr_src, const int* __restrict__ row_off,
                      const int* __restrict__ deg, const _Float16* __restrict__ XL16,
                      const _Float16* __restrict__ XR16, const float* __restrict__ att,
                      const float* __restrict__ gb, const float* __restrict__ lng,
                      const float* __restrict__ lnb, _Float16* __restrict__ Y16, int N) {
  int n = blockIdx.x * (blockDim.x >> 6) + (threadIdx.x >> 6);
  int j = threadIdx.x & 63;
  if (n >= N) return;
  float xr = (float)XR16[(size_t)n * HDIM + j];
  float attv = att[j];
  unsigned xr_pk  = cvt_pk_u(xr, xr);
  unsigned att_pk = cvt_pk_u(attv, attv);
  unsigned c02_pk = 0x32663266u;                    // (0.2, 0.2) f16
  fp16x2 one_pk = as_h2(0x3C003C00u);               // (1.0, 1.0) f16
  const unsigned short* XLu = (const unsigned short*)XL16;
  unsigned ju = (unsigned)j;

  // self-loop (f32 path)
  float xl = (float)XL16[(size_t)n * HDIM + j];
  float p = head_reduce32(lrelu_(xl + xr) * attv);
  float ex = __expf(p);
  float acc0 = ex * xl, acc1 = 0.f;
  float den0 = ex, den1 = 0.f;

  int base = row_off[n], cnt = deg[n];
  for (int c0 = 0; c0 < cnt; c0 += 64) {
    int m_ = cnt - c0; if (m_ > 64) m_ = 64;
    int sidx = (j < m_) ? csr_src[base + c0 + j] : 0;
    int npairs = m_ >> 1;
    int pp = 0;
    // ---- full 8-pair groups, unmasked ----
    for (; pp + 8 <= npairs; pp += 8) {
      unsigned x[8];
#pragma unroll
      for (int u = 0; u < 8; ++u) {
        int sa = __builtin_amdgcn_readlane(sidx, 2 * (pp + u));
        int sb = __builtin_amdgcn_readlane(sidx, 2 * (pp + u) + 1);
        unsigned ua = XLu[((unsigned)sa << 6) + ju];
        unsigned ub = XLu[((unsigned)sb << 6) + ju];
        x[u] = __builtin_amdgcn_perm(ub, ua, 0x05040100u);
      }
#pragma unroll
      for (int u = 0; u < 8; ++u) {
        unsigned t = pk_add(x[u], xr_pk);
        unsigned lr = pk_max(t, pk_mul(t, c02_pk));
        unsigned sc = pk_mul(lr, att_pk);
        sc = pk_reduce32(sc);
        float s_a = cvt_lo(sc), s_b = cvt_lo(sc >> 16);
        float e_a = __expf(s_a), e_b = __expf(s_b);
        fp16x2 exk = __builtin_amdgcn_cvt_pkrtz(e_a, e_b);
        if (u & 1) {
          acc1 = __builtin_amdgcn_fdot2(as_h2(x[u]), exk, acc1, false);
          den1 = __builtin_amdgcn_fdot2(exk, one_pk, den1, false);
        } else {
          acc0 = __builtin_amdgcn_fdot2(as_h2(x[u]), exk, acc0, false);
          den0 = __builtin_amdgcn_fdot2(exk, one_pk, den0, false);
        }
      }
    }
    // ---- remaining pairs ----
    for (; pp < npairs; ++pp) {
      int sa = __builtin_amdgcn_readlane(sidx, 2 * pp);
      int sb = __builtin_amdgcn_readlane(sidx, 2 * pp + 1);
      unsigned ua = XLu[((unsigned)sa << 6) + ju];
      unsigned ub = XLu[((unsigned)sb << 6) + ju];
      unsigned xu = __builtin_amdgcn_perm(ub, ua, 0x05040100u);
      unsigned t = pk_add(xu, xr_pk);
      unsigned lr = pk_max(t, pk_mul(t, c02_pk));
      unsigned sc = pk_mul(lr, att_pk);
      sc = pk_reduce32(sc);
      float s_a = cvt_lo(sc), s_b = cvt_lo(sc >> 16);
      float e_a = __expf(s_a), e_b = __expf(s_b);
      fp16x2 exk = __builtin_amdgcn_cvt_pkrtz(e_a, e_b);
      acc0 = __builtin_amdgcn_fdot2(as_h2(xu), exk, acc0, false);
      den0 = __builtin_amdgcn_fdot2(exk, one_pk, den0, false);
    }
    if (m_ & 1) {   // odd edge, f32 path
      int s = __builtin_amdgcn_readlane(sidx, m_ - 1);
      float xls = (float)XL16[(size_t)s * HDIM + j];
      float pq = head_reduce32(lrelu_(xls + xr) * attv);
      float ee = __expf(pq);
      acc0 += ee * xls;
      den0 += ee;
    }
  }

  float acc = acc0 + acc1;
  float den = den0 + den1;
  float y = acc / (den + 1e-16f) + gb[j];
  y = y > 0.f ? y : __expf(y) - 1.f;
  float mu = full_reduce64(y) * (1.f / 64.f);
  float d = y - mu;
  float var = full_reduce64(d * d) * (1.f / 64.f);
  Y16[(size_t)n * HDIM + j] = (_Float16)(d * rsqrtf(var + 1e-5f) * lng[j] + lnb[j]);
}

// ======================= k3: Y16 -> XL2(f16)/XR2(f16) via f16 MFMA =======================
__global__ void __launch_bounds__(256) k3_mfma(const _Float16* __restrict__ Y16,
                      const _Float16* __restrict__ Wb, _Float16* __restrict__ XL16,
                      _Float16* __restrict__ XR16, int N) {
  __shared__ _Float16 W[128 * GSTR];
  for (int i = threadIdx.x; i < 128 * GSTR / 8; i += 256)
    ((int4*)W)[i] = ((const int4*)Wb)[i];
  __syncthreads();
  int wave = blockIdx.x * 4 + (threadIdx.x >> 6);
  int nwaves = gridDim.x * 4;
  int lane = threadIdx.x & 63;
  int c = lane & 15, q = lane >> 4;
  for (int n0 = wave * 16; n0 < N; n0 += nwaves * 16) {
    bool okrow = (n0 + c) < N;
    const _Float16* yrow = Y16 + (size_t)(n0 + c) * HDIM + q * 8;
    half8 a0 = {0, 0, 0, 0, 0, 0, 0, 0}, a1 = {0, 0, 0, 0, 0, 0, 0, 0};
    if (okrow) {
      a0 = *(const half8*)(yrow);
      a1 = *(const half8*)(yrow + 32);
    }

    f32x4 acc[8];
#pragma unroll
    for (int t = 0; t < 8; ++t) acc[t] = (f32x4){0.f, 0.f, 0.f, 0.f};
#pragma unroll
    for (int t = 0; t < 8; ++t) {
      half8 b0 = *(const half8*)(&W[(t * 16 + c) * GSTR + q * 8]);
      half8 b1 = *(const half8*)(&W[(t * 16 + c) * GSTR + 32 + q * 8]);
      acc[t] = __builtin_amdgcn_mfma_f32_16x16x32_f16(a0, b0, acc[t], 0, 0, 0);
      acc[t] = __builtin_amdgcn_mfma_f32_16x16x32_f16(a1, b1, acc[t], 0, 0, 0);
    }
#pragma unroll
    for (int t = 0; t < 4; ++t) {
#pragma unroll
      for (int i = 0; i < 4; ++i) {
        int n = n0 + q * 4 + i;
        if (n < N) {
          XL16[(size_t)n * HDIM + t * 16 + c] = (_Float16)acc[t][i];
          XR16[(size_t)n * HDIM + t * 16 + c] = (_Float16)acc[t + 4][i];
        }
      }
    }
  }
}

// ======================= k5: GRU via f16 MFMA + heads =======================
__global__ void __launch_bounds__(256) k5_gru_mfma(const _Float16* __restrict__ Y16,
                       const _Float16* __restrict__ Wt,
                       const float* __restrict__ bi, const float* __restrict__ bh,
                       const float* __restrict__ huW, const float* __restrict__ hub,
                       const float* __restrict__ hfW, const float* __restrict__ hfb,
                       const float* __restrict__ hoW, const float* __restrict__ hob,
                       const float* __restrict__ hcW, const float* __restrict__ hcb,
                       float* __restrict__ out, int N) {
  __shared__ _Float16 W[192 * GSTR];
  __shared__ float BS[192];
  __shared__ float BHN[64];
  for (int i = threadIdx.x; i < 192 * GSTR / 8; i += 256)
    ((int4*)W)[i] = ((const int4*)Wt)[i];
  for (int i = threadIdx.x; i < 192; i += 256) BS[i] = bi[i] + (i < 128 ? bh[i] : 0.f);
  for (int i = threadIdx.x; i < 64; i += 256) BHN[i] = bh[128 + i];
  __syncthreads();

  int wave = blockIdx.x * 4 + (threadIdx.x >> 6);
  int nwaves = gridDim.x * 4;
  int lane = threadIdx.x & 63;
  int c = lane & 15, q = lane >> 4;

  float hu_[4], hf_[4], ho_[4], hc_[4];
#pragma unroll
  for (int t = 0; t < 4; ++t) {
    hu_[t] = huW[t * 16 + c];
    hf_[t] = hfW[t * 16 + c];
    ho_[t] = hoW[t * 16 + c];
    hc_[t] = hcW[t * 16 + c];
  }
  float hub0 = hub[0], hfb0 = hfb[0], hob0 = hob[0], hcb0 = hcb[0];

  for (int n0 = wave * 16; n0 < N; n0 += nwaves * 16) {
    bool okrow = (n0 + c) < N;
    const _Float16* yrow = Y16 + (size_t)(n0 + c) * HDIM + q * 8;
    half8 a0 = {0, 0, 0, 0, 0, 0, 0, 0}, a1 = {0, 0, 0, 0, 0, 0, 0, 0};
    if (okrow) {
      a0 = *(const half8*)(yrow);
      a1 = *(const half8*)(yrow + 32);
    }

    f32x4 acc[12];
#pragma unroll
    for (int t = 0; t < 12; ++t) acc[t] = (f32x4){0.f, 0.f, 0.f, 0.f};
#pragma unroll
    for (int t = 0; t < 12; ++t) {
      half8 b0 = *(const half8*)(&W[(t * 16 + c) * GSTR + q * 8]);
      half8 b1 = *(const half8*)(&W[(t * 16 + c) * GSTR + 32 + q * 8]);
      acc[t] = __builtin_amdgcn_mfma_f32_16x16x32_f16(a0, b0, acc[t], 0, 0, 0);
      acc[t] = __builtin_amdgcn_mfma_f32_16x16x32_f16(a1, b1, acc[t], 0, 0, 0);
    }

    float hv[4][4];
#pragma unroll
    for (int t = 0; t < 4; ++t) {
      int cr = t * 16 + c;
      float bsr = BS[cr], bsz = BS[64 + cr], bsn = BS[128 + cr], bhn = BHN[cr];
#pragma unroll
      for (int i = 0; i < 4; ++i) {
        float r = sigmoidf_(acc[t][i] + bsr);
        float z = sigmoidf_(acc[t + 4][i] + bsz);
        float nn = tanhf(acc[t + 8][i] + bsn + r * bhn);
        hv[t][i] = (1.f - z) * nn;
      }
    }
#pragma unroll
    for (int i = 0; i < 4; ++i) {
      float pu = 0.f, pf = 0.f, po = 0.f, pc = 0.f;
#pragma unroll
      for (int t = 0; t < 4; ++t) {
        pu += hv[t][i] * hu_[t];
        pf += hv[t][i] * hf_[t];
        po += hv[t][i] * ho_[t];
        pc += hv[t][i] * hc_[t];
      }
      pu = reduce16(pu); pf = reduce16(pf); po = reduce16(po); pc = reduce16(pc);
      int n = n0 + q * 4 + i;
      if (n < N) {
        if (c == 0) out[n]         = sigmoidf_(pu + hub0);
        if (c == 1) out[N + n]     = sigmoidf_(pf + hfb0);
        if (c == 2) out[2 * N + n] = fmaxf(po + hob0, 0.f);
        if (c == 3) out[3 * N + n] = sigmoidf_(pc + hcb0);
      }
    }
  }
}

// ======================= launch =======================
extern "C" void kernel_launch(void* const* d_in, const int* in_sizes, int n_in,
                              void* d_out, int out_size, void* d_ws, size_t ws_size,
                              hipStream_t stream) {
  const float* nf    = (const float*)d_in[0];
  const int*   ei    = (const int*)d_in[1];
  const float* projW = (const float*)d_in[2];
  const float* projB = (const float*)d_in[3];
  const float* g1Wl  = (const float*)d_in[4];
  const float* g1Wr  = (const float*)d_in[5];
  const float* g1att = (const float*)d_in[6];
  const float* g1b   = (const float*)d_in[7];
  const float* g2Wl  = (const float*)d_in[8];
  const float* g2Wr  = (const float*)d_in[9];
  const float* g2att = (const float*)d_in[10];
  const float* g2b   = (const float*)d_in[11];
  const float* ln1g  = (const float*)d_in[12];
  const float* ln1b  = (const float*)d_in[13];
  const float* ln2g  = (const float*)d_in[14];
  const float* ln2b  = (const float*)d_in[15];
  const float* gruWi = (const float*)d_in[16];
  // d_in[17] = gru_Wh, unused (h0 = 0)
  const float* gruBi = (const float*)d_in[18];
  const float* gruBh = (const float*)d_in[19];
  const float* huW = (const float*)d_in[20];
  const float* hub = (const float*)d_in[21];
  const float* hfW = (const float*)d_in[22];
  const float* hfb = (const float*)d_in[23];
  const float* hoW = (const float*)d_in[24];
  const float* hob = (const float*)d_in[25];
  const float* hcW = (const float*)d_in[26];
  const float* hcb = (const float*)d_in[27];
  float* out = (float*)d_out;

  const int N = in_sizes[0] / NDIM;
  const int E = in_sizes[1] / 2;
  int bsh = 8;
  while (((N - 1) >> bsh) >= NB) ++bsh;
  const int nbu = (N + (1 << bsh) - 1) >> bsh;
  const int cap = (E + nbu - 1) / nbu + 768;   // +12 sigma over Poisson mean

  char* ws = (char*)d_ws;
  size_t off = 0;
  auto carve = [&](size_t bytes) { void* p = ws + off; off += (bytes + 255) & ~size_t(255); return p; };
  _Float16*  XL16    = (_Float16*)carve(sizeof(_Float16) * N * HDIM);
  _Float16*  XR16    = (_Float16*)carve(sizeof(_Float16) * N * HDIM);
  _Float16*  Y16     = (_Float16*)carve(sizeof(_Float16) * N * HDIM);
  unsigned*  pairs   = (unsigned*)carve(sizeof(unsigned) * (size_t)nbu * cap);
  int*       csr_src = (int*)carve(sizeof(int) * (size_t)nbu * cap);
  int*       deg     = (int*)carve(sizeof(int) * N);
  int*       row_off = (int*)carve(sizeof(int) * N);
  int*       bcur    = (int*)carve(sizeof(int) * NB);
  float*     Wfl     = (float*)carve(sizeof(float) * NDIM * HDIM);
  float*     Wfr     = (float*)carve(sizeof(float) * NDIM * HDIM);
  float*     bfl     = (float*)carve(sizeof(float) * HDIM);
  float*     bfr     = (float*)carve(sizeof(float) * HDIM);
  _Float16*  Wt      = (_Float16*)carve(sizeof(_Float16) * 192 * GSTR);
  _Float16*  Wb      = (_Float16*)carve(sizeof(_Float16) * 128 * GSTR);

  const int BLK = 256;
  dim3 b(BLK);
  dim3 gridWaveN((N + 3) / 4);
  const int nBin = (E + BLK * EPB - 1) / (BLK * EPB);

  // ---- D0: zero bucket cursors (offsets from base) ----
  (void)hipMemsetAsync(bcur, 0, sizeof(int) * NB, stream);
  // ---- D1: bin + weight prep ----
  k_bin_wprep<<<dim3(nBin + 84), b, 0, stream>>>(ei, pairs, bcur, E, bsh, cap, nBin,
                                                 projW, projB, g1Wl, g1Wr, gruWi, g2Wl, g2Wr,
                                                 Wfl, Wfr, bfl, bfr, Wt, Wb);
  // ---- D2: per-bucket CSR + k1 ----
  k_csr_k1<<<dim3(nbu + (N + 3) / 4), b, 0, stream>>>(pairs, bcur, row_off, deg, csr_src,
                                                      N, bsh, cap, nbu,
                                                      nf, Wfl, Wfr, bfl, bfr, XL16, XR16);
  // ---- D3..D6 ----
  k_agg<<<gridWaveN, b, 0, stream>>>(csr_src, row_off, deg, XL16, XR16, g1att, g1b, ln1g, ln1b, Y16, N);
  k3_mfma<<<dim3(800), b, 0, stream>>>(Y16, Wb, XL16, XR16, N);
  k_agg<<<gridWaveN, b, 0, stream>>>(csr_src, row_off, deg, XL16, XR16, g2att, g2b, ln2g, ln2b, Y16, N);
  k5_gru_mfma<<<dim3(800), b, 0, stream>>>(Y16, Wt, gruBi, gruBh,
                                           huW, hub, hfW, hfb, hoW, hob, hcW, hcb, out, N);
}